// Round 2
// baseline (907.677 us; speedup 1.0000x reference)
//
#include <hip/hip_runtime.h>

typedef _Float16 half4v __attribute__((ext_vector_type(4)));
typedef _Float16 half8v __attribute__((ext_vector_type(8)));
typedef float f32x4 __attribute__((ext_vector_type(4)));
typedef float f32x2 __attribute__((ext_vector_type(2)));

#define HD 4096
#define HH (4096 * 4096)

__device__ __forceinline__ unsigned int pack4(float a, float b, float c, float d) {
    int w = 0;
    w = __builtin_amdgcn_cvt_pk_fp8_f32(a, b, w, false);
    w = __builtin_amdgcn_cvt_pk_fp8_f32(c, d, w, true);
    return (unsigned int)w;
}

__device__ __forceinline__ void gload16(const _Float16* g, _Float16* l) {
    __builtin_amdgcn_global_load_lds(
        (const __attribute__((address_space(1))) unsigned int*)g,
        (__attribute__((address_space(3))) unsigned int*)l, 16, 0, 0);
}

// ---------- f32 -> f16 ----------
__global__ __launch_bounds__(256) void k_f32_to_f16(const float* __restrict__ s,
                                                    _Float16* __restrict__ d, int n4) {
    int i = blockIdx.x * 256 + threadIdx.x;
    if (i >= n4) return;
    float4 v = ((const float4*)s)[i];
    half4v o = {(_Float16)v.x, (_Float16)v.y, (_Float16)v.z, (_Float16)v.w};
    ((half4v*)d)[i] = o;
}

// ---------- exp: p (f32) -> E (f16), 16 elems/thread ----------
__global__ __launch_bounds__(256) void k_exp(const float* __restrict__ p0,
                                             const float* __restrict__ p1,
                                             _Float16* __restrict__ E0,
                                             _Float16* __restrict__ E1) {
    const float* p = blockIdx.z ? p1 : p0;
    _Float16* E = blockIdx.z ? E1 : E0;
    size_t i = (size_t)blockIdx.x * 256 + threadIdx.x;
    const float4* ps = (const float4*)p + i * 4;
    float4 v0 = ps[0], v1 = ps[1], v2 = ps[2], v3 = ps[3];
    half8v h0 = {(_Float16)__expf(v0.x), (_Float16)__expf(v0.y),
                 (_Float16)__expf(v0.z), (_Float16)__expf(v0.w),
                 (_Float16)__expf(v1.x), (_Float16)__expf(v1.y),
                 (_Float16)__expf(v1.z), (_Float16)__expf(v1.w)};
    half8v h1 = {(_Float16)__expf(v2.x), (_Float16)__expf(v2.y),
                 (_Float16)__expf(v2.z), (_Float16)__expf(v2.w),
                 (_Float16)__expf(v3.x), (_Float16)__expf(v3.y),
                 (_Float16)__expf(v3.z), (_Float16)__expf(v3.w)};
    half8v* Ev = (half8v*)E + i * 2;
    Ev[0] = h0;
    Ev[1] = h1;
}

// ---------- E -> ET (f16 transpose) + F (fp8) + FT (fp8), 64x64 tiles ----------
// F and FT are exact transposes (both derived from the same f16 values).
__global__ __launch_bounds__(256) void k_trans16(const _Float16* __restrict__ E0in,
                                                 const _Float16* __restrict__ E1in,
                                                 _Float16* __restrict__ ET0,
                                                 _Float16* __restrict__ ET1,
                                                 unsigned int* __restrict__ F0,
                                                 unsigned int* __restrict__ F1,
                                                 unsigned int* __restrict__ FT0,
                                                 unsigned int* __restrict__ FT1) {
    int z = blockIdx.z;
    const _Float16* E = z ? E1in : E0in;
    _Float16* ET = z ? ET1 : ET0;
    unsigned int* F = z ? F1 : F0;
    unsigned int* FT = z ? FT1 : FT0;
    __shared__ _Float16 tile[64][72];
    int t = threadIdx.x;
    int r = t >> 2, c16 = (t & 3) * 16;
    int row = blockIdx.y * 64 + r;
    int col0 = blockIdx.x * 64 + c16;
    const _Float16* src = E + (size_t)row * HD + col0;
    half8v a = *(const half8v*)src;
    half8v b = *(const half8v*)(src + 8);
    uint4 fo;
    fo.x = pack4(a[0], a[1], a[2], a[3]);
    fo.y = pack4(a[4], a[5], a[6], a[7]);
    fo.z = pack4(b[0], b[1], b[2], b[3]);
    fo.w = pack4(b[4], b[5], b[6], b[7]);
    *(uint4*)(F + (size_t)row * (HD / 4) + (col0 >> 2)) = fo;
    *(half8v*)&tile[r][c16] = a;
    *(half8v*)&tile[r][c16 + 8] = b;
    __syncthreads();
    int j = r;  // output row within tile
    half8v oa, ob;
#pragma unroll
    for (int u = 0; u < 8; ++u) oa[u] = tile[c16 + u][j];
#pragma unroll
    for (int u = 0; u < 8; ++u) ob[u] = tile[c16 + 8 + u][j];
    size_t orow = (size_t)(blockIdx.x * 64 + j);
    _Float16* dst = ET + orow * HD + blockIdx.y * 64 + c16;
    *(half8v*)dst = oa;
    *(half8v*)(dst + 8) = ob;
    uint4 ft;
    ft.x = pack4(oa[0], oa[1], oa[2], oa[3]);
    ft.y = pack4(oa[4], oa[5], oa[6], oa[7]);
    ft.z = pack4(ob[0], ob[1], ob[2], ob[3]);
    ft.w = pack4(ob[4], ob[5], ob[6], ob[7]);
    *(uint4*)(FT + orow * (HD / 4) + ((blockIdx.y * 64 + c16) >> 2)) = ft;
}

// ---------- Sinkhorn phase: vout[row] = rcp( sum_j M[row][j] * vin[j] ) ----------
__global__ __launch_bounds__(256) void k_phase(const unsigned int* __restrict__ M0,
                                               const unsigned int* __restrict__ M1,
                                               const float* __restrict__ vin,
                                               float* __restrict__ vout, int first) {
    int b = blockIdx.x, t = threadIdx.x;
    int wave = t >> 6, lane = t & 63;
    int w = b * 4 + wave;  // 0..8191
    int m = w >> 12;
    int row = w & 4095;
    const unsigned int* r0 = (m ? M1 : M0) + (size_t)row * (HD / 4);
    const float* vm = vin + m * HD;
    float acc = 0.f;
#pragma unroll
    for (int c = 0; c < 4; ++c) {
        int j = c * 1024 + lane * 16;
        uint4 e = *(const uint4*)(r0 + (j >> 2));
        f32x2 a0 = __builtin_amdgcn_cvt_pk_f32_fp8((int)e.x, false);
        f32x2 a1 = __builtin_amdgcn_cvt_pk_f32_fp8((int)e.x, true);
        f32x2 a2 = __builtin_amdgcn_cvt_pk_f32_fp8((int)e.y, false);
        f32x2 a3 = __builtin_amdgcn_cvt_pk_f32_fp8((int)e.y, true);
        f32x2 a4 = __builtin_amdgcn_cvt_pk_f32_fp8((int)e.z, false);
        f32x2 a5 = __builtin_amdgcn_cvt_pk_f32_fp8((int)e.z, true);
        f32x2 a6 = __builtin_amdgcn_cvt_pk_f32_fp8((int)e.w, false);
        f32x2 a7 = __builtin_amdgcn_cvt_pk_f32_fp8((int)e.w, true);
        if (first) {
            acc += (a0.x + a0.y) + (a1.x + a1.y) + (a2.x + a2.y) + (a3.x + a3.y);
            acc += (a4.x + a4.y) + (a5.x + a5.y) + (a6.x + a6.y) + (a7.x + a7.y);
        } else {
            float4 s0 = *(const float4*)(vm + j);
            float4 s1 = *(const float4*)(vm + j + 4);
            float4 s2 = *(const float4*)(vm + j + 8);
            float4 s3 = *(const float4*)(vm + j + 12);
            acc += a0.x * s0.x + a0.y * s0.y + a1.x * s0.z + a1.y * s0.w;
            acc += a2.x * s1.x + a2.y * s1.y + a3.x * s1.z + a3.y * s1.w;
            acc += a4.x * s2.x + a4.y * s2.y + a5.x * s2.z + a5.y * s2.w;
            acc += a6.x * s3.x + a6.y * s3.y + a7.x * s3.z + a7.y * s3.w;
        }
    }
#pragma unroll
    for (int off = 32; off; off >>= 1) acc += __shfl_xor(acc, off, 64);
    if (lane == 0) vout[m * HD + row] = __builtin_amdgcn_rcpf(acc);
}

// ---------- GEMM C = A * B^T, 128x128 tile, BK=64, global_load_lds staging ----------
// All operands f16 row-major; split-K partials into Cp slices.
__global__ __launch_bounds__(256, 2) void k_gemm(const _Float16* __restrict__ A,
                                                 const _Float16* __restrict__ B,
                                                 float* __restrict__ Cp,
                                                 int M, int N, int K, int kChunk) {
    __shared__ _Float16 As[128 * 64];  // [row][k] linear, 16KB
    __shared__ _Float16 Bs[128 * 64];
    int t = threadIdx.x;
    int w = t >> 6, lane = t & 63;
    int bn = blockIdx.x * 128, bm = blockIdx.y * 128;
    int k0beg = blockIdx.z * kChunk, k0end = k0beg + kChunk;
    int rm = (w >> 1) * 64, wn = (w & 1) * 64;  // wave's 64x64 output quadrant
    int r16 = lane & 15, kq = lane >> 4;
    int srow = lane >> 3, scol = (lane & 7) * 8;  // staging lane mapping
    const _Float16* Ab = A + (size_t)(bm + w * 32 + srow) * K + scol;
    const _Float16* Bb = B + (size_t)(bn + w * 32 + srow) * K + scol;
    _Float16* AsW = As + (w * 32) * 64;
    _Float16* BsW = Bs + (w * 32) * 64;
    f32x4 acc[4][4];
#pragma unroll
    for (int m2 = 0; m2 < 4; ++m2)
#pragma unroll
        for (int n2 = 0; n2 < 4; ++n2) acc[m2][n2] = (f32x4){0.f, 0.f, 0.f, 0.f};
    for (int k0 = k0beg; k0 < k0end; k0 += 64) {
        __syncthreads();  // prior readers done before overwrite
#pragma unroll
        for (int i = 0; i < 4; ++i) {
            gload16(Ab + (size_t)(i * 8) * K + k0, AsW + i * 8 * 64);
            gload16(Bb + (size_t)(i * 8) * K + k0, BsW + i * 8 * 64);
        }
        __syncthreads();  // vmcnt(0) drain + barrier
#pragma unroll
        for (int s2 = 0; s2 < 2; ++s2) {
            half8v af[4], bf[4];
#pragma unroll
            for (int m2 = 0; m2 < 4; ++m2)
                af[m2] = *(const half8v*)&As[(rm + m2 * 16 + r16) * 64 + s2 * 32 + kq * 8];
#pragma unroll
            for (int n2 = 0; n2 < 4; ++n2)
                bf[n2] = *(const half8v*)&Bs[(wn + n2 * 16 + r16) * 64 + s2 * 32 + kq * 8];
#pragma unroll
            for (int m2 = 0; m2 < 4; ++m2)
#pragma unroll
                for (int n2 = 0; n2 < 4; ++n2)
                    acc[m2][n2] = __builtin_amdgcn_mfma_f32_16x16x32_f16(af[m2], bf[n2],
                                                                         acc[m2][n2], 0, 0, 0);
        }
    }
    float* out = Cp + (size_t)blockIdx.z * M * N;
#pragma unroll
    for (int m2 = 0; m2 < 4; ++m2) {
#pragma unroll
        for (int n2 = 0; n2 < 4; ++n2) {
            int row0 = bm + rm + m2 * 16 + kq * 4;
            int col0 = bn + wn + n2 * 16 + r16;
#pragma unroll
            for (int rr = 0; rr < 4; ++rr)
                out[(size_t)(row0 + rr) * N + col0] = acc[m2][n2][rr];
        }
    }
}

// ---------- split-K reduce + fused Sinkhorn diagonal scales + relu + convert ----------
// mode 0: none; 1: v*=sc[col]; 2: v=relu(v*sc)*sc*4096; 3: v*=sc[col]/4096
__global__ __launch_bounds__(256) void k_reduce(const float* __restrict__ Cp, void* __restrict__ out,
                                                int MN, int KS, int mode,
                                                const float* __restrict__ sc, int of32) {
    size_t idx = ((size_t)blockIdx.x * 256 + threadIdx.x) * 8;
    if (idx >= (size_t)MN) return;
    float4 s0 = *(const float4*)(Cp + idx);
    float4 s1 = *(const float4*)(Cp + idx + 4);
    for (int z = 1; z < KS; ++z) {
        const float* p = Cp + (size_t)z * MN + idx;
        float4 v0 = *(const float4*)p;
        float4 v1 = *(const float4*)(p + 4);
        s0.x += v0.x; s0.y += v0.y; s0.z += v0.z; s0.w += v0.w;
        s1.x += v1.x; s1.y += v1.y; s1.z += v1.z; s1.w += v1.w;
    }
    if (mode) {
        int col = (int)(idx & (HD - 1));
        float4 a0 = *(const float4*)(sc + col);
        float4 a1 = *(const float4*)(sc + col + 4);
        if (mode == 1) {
            s0.x *= a0.x; s0.y *= a0.y; s0.z *= a0.z; s0.w *= a0.w;
            s1.x *= a1.x; s1.y *= a1.y; s1.z *= a1.z; s1.w *= a1.w;
        } else if (mode == 2) {
            s0.x = fmaxf(s0.x * a0.x, 0.f) * a0.x * 4096.f;
            s0.y = fmaxf(s0.y * a0.y, 0.f) * a0.y * 4096.f;
            s0.z = fmaxf(s0.z * a0.z, 0.f) * a0.z * 4096.f;
            s0.w = fmaxf(s0.w * a0.w, 0.f) * a0.w * 4096.f;
            s1.x = fmaxf(s1.x * a1.x, 0.f) * a1.x * 4096.f;
            s1.y = fmaxf(s1.y * a1.y, 0.f) * a1.y * 4096.f;
            s1.z = fmaxf(s1.z * a1.z, 0.f) * a1.z * 4096.f;
            s1.w = fmaxf(s1.w * a1.w, 0.f) * a1.w * 4096.f;
        } else {
            const float inv = 1.f / 4096.f;
            s0.x *= a0.x * inv; s0.y *= a0.y * inv; s0.z *= a0.z * inv; s0.w *= a0.w * inv;
            s1.x *= a1.x * inv; s1.y *= a1.y * inv; s1.z *= a1.z * inv; s1.w *= a1.w * inv;
        }
    }
    if (of32) {
        *(float4*)((float*)out + idx) = s0;
        *(float4*)((float*)out + idx + 4) = s1;
    } else {
        half8v o = {(_Float16)s0.x, (_Float16)s0.y, (_Float16)s0.z, (_Float16)s0.w,
                    (_Float16)s1.x, (_Float16)s1.y, (_Float16)s1.z, (_Float16)s1.w};
        *(half8v*)((_Float16*)out + idx) = o;
    }
}

extern "C" void kernel_launch(void* const* d_in, const int* in_sizes, int n_in,
                              void* d_out, int out_size, void* d_ws, size_t ws_size,
                              hipStream_t stream) {
    const float* x  = (const float*)d_in[0];
    const float* W1 = (const float*)d_in[1];
    const float* W2 = (const float*)d_in[3];
    const float* W3 = (const float*)d_in[5];
    const float* p0 = (const float*)d_in[7];
    const float* p1 = (const float*)d_in[8];

    char* ws = (char*)d_ws;
    size_t off = 0;
    auto alloc = [&](size_t bytes) -> void* {
        void* p = ws + off;
        off += (bytes + 255) & ~(size_t)255;
        return p;
    };
    _Float16* E0 = (_Float16*)alloc((size_t)HH * 2);
    _Float16* E1 = (_Float16*)alloc((size_t)HH * 2);
    _Float16* ET0 = (_Float16*)alloc((size_t)HH * 2);
    _Float16* ET1 = (_Float16*)alloc((size_t)HH * 2);
    unsigned int* F0 = (unsigned int*)alloc((size_t)HH);   // fp8; later aliased as Cp
    unsigned int* F1 = (unsigned int*)alloc((size_t)HH);
    unsigned int* FT0 = (unsigned int*)alloc((size_t)HH);  // fp8 T; later aliased as W2h
    unsigned int* FT1 = (unsigned int*)alloc((size_t)HH);
    _Float16* W1h = (_Float16*)alloc((size_t)4096 * 1024 * 2);
    _Float16* W3h = (_Float16*)alloc((size_t)1024 * 4096 * 2);
    _Float16* xh = (_Float16*)alloc(256 * 1024 * 2);
    _Float16* Aa = (_Float16*)alloc(256 * 4096 * 2);
    _Float16* Ab = (_Float16*)alloc(256 * 4096 * 2);
    float* invR = (float*)alloc(2 * 4096 * 4);
    float* invS = (float*)alloc(2 * 4096 * 4);
    float* Cp = (float*)F0;          // 33.5 MB (F0+F1), dead after sinkhorn
    _Float16* W2h = (_Float16*)FT0;  // 33.5 MB (FT0+FT1), dead after sinkhorn

    // precompute
    k_f32_to_f16<<<256, 256, 0, stream>>>(x, xh, 65536);
    k_f32_to_f16<<<4096, 256, 0, stream>>>(W1, W1h, 1048576);
    k_f32_to_f16<<<4096, 256, 0, stream>>>(W3, W3h, 1048576);
    k_exp<<<dim3(4096, 1, 2), 256, 0, stream>>>(p0, p1, E0, E1);
    k_trans16<<<dim3(64, 64, 2), 256, 0, stream>>>(E0, E1, ET0, ET1, F0, F1, FT0, FT1);

    // 20 Sinkhorn iterations
    for (int it = 0; it < 20; ++it) {
        k_phase<<<2048, 256, 0, stream>>>(F0, F1, invS, invR, it == 0);
        k_phase<<<2048, 256, 0, stream>>>(FT0, FT1, invR, invS, 0);
    }

    // W2 -> f16 into FT region (FT dead now)
    k_f32_to_f16<<<16384, 256, 0, stream>>>(W2, W2h, 4194304);

    // MLP chain; P = diag(r) E diag(s) fused into reduce epilogues
    k_gemm<<<dim3(32, 2, 8), 256, 0, stream>>>(xh, W1h, Cp, 256, 4096, 1024, 128);
    k_reduce<<<512, 256, 0, stream>>>(Cp, Aa, 1048576, 8, 1, invS, 0);
    k_gemm<<<dim3(32, 2, 8), 256, 0, stream>>>(Aa, E0, Cp, 256, 4096, 4096, 512);
    k_reduce<<<512, 256, 0, stream>>>(Cp, Ab, 1048576, 8, 2, invR, 0);
    k_gemm<<<dim3(32, 2, 8), 256, 0, stream>>>(Ab, ET0, Cp, 256, 4096, 4096, 512);
    k_reduce<<<512, 256, 0, stream>>>(Cp, Aa, 1048576, 8, 3, invS, 0);
    k_gemm<<<dim3(32, 2, 8), 256, 0, stream>>>(Aa, W2h, Cp, 256, 4096, 4096, 512);
    k_reduce<<<512, 256, 0, stream>>>(Cp, Ab, 1048576, 8, 1, invS + HD, 0);
    k_gemm<<<dim3(32, 2, 8), 256, 0, stream>>>(Ab, E1, Cp, 256, 4096, 4096, 512);
    k_reduce<<<512, 256, 0, stream>>>(Cp, Aa, 1048576, 8, 2, invR + HD, 0);
    k_gemm<<<dim3(32, 2, 8), 256, 0, stream>>>(Aa, ET1, Cp, 256, 4096, 4096, 512);
    k_reduce<<<512, 256, 0, stream>>>(Cp, Ab, 1048576, 8, 3, invS + HD, 0);
    k_gemm<<<dim3(8, 2, 32), 256, 0, stream>>>(Ab, W3h, Cp, 256, 1024, 4096, 128);
    k_reduce<<<128, 256, 0, stream>>>(Cp, d_out, 262144, 32, 0, nullptr, 1);

    (void)in_sizes; (void)n_in; (void)out_size; (void)ws_size;
}

// Round 3
// 893.978 us; speedup vs baseline: 1.0153x; 1.0153x over previous
//
#include <hip/hip_runtime.h>

typedef _Float16 half4v __attribute__((ext_vector_type(4)));
typedef _Float16 half8v __attribute__((ext_vector_type(8)));
typedef float f32x4 __attribute__((ext_vector_type(4)));
typedef float f32x2 __attribute__((ext_vector_type(2)));

#define HD 4096
#define HH (4096 * 4096)

__device__ __forceinline__ unsigned int pack4(float a, float b, float c, float d) {
    int w = 0;
    w = __builtin_amdgcn_cvt_pk_fp8_f32(a, b, w, false);
    w = __builtin_amdgcn_cvt_pk_fp8_f32(c, d, w, true);
    return (unsigned int)w;
}

__device__ __forceinline__ void gload16(const _Float16* g, _Float16* l) {
    __builtin_amdgcn_global_load_lds(
        (const __attribute__((address_space(1))) unsigned int*)g,
        (__attribute__((address_space(3))) unsigned int*)l, 16, 0, 0);
}

// ---------- f32 -> f16 ----------
__global__ __launch_bounds__(256) void k_f32_to_f16(const float* __restrict__ s,
                                                    _Float16* __restrict__ d, int n4) {
    int i = blockIdx.x * 256 + threadIdx.x;
    if (i >= n4) return;
    float4 v = ((const float4*)s)[i];
    half4v o = {(_Float16)v.x, (_Float16)v.y, (_Float16)v.z, (_Float16)v.w};
    ((half4v*)d)[i] = o;
}

// ---------- exp: p (f32) -> E (f16), one float4 per thread, fully coalesced ----------
__global__ __launch_bounds__(256) void k_exp(const float* __restrict__ p0,
                                             const float* __restrict__ p1,
                                             _Float16* __restrict__ E0,
                                             _Float16* __restrict__ E1) {
    const float* p = blockIdx.z ? p1 : p0;
    _Float16* E = blockIdx.z ? E1 : E0;
    size_t i = (size_t)blockIdx.x * 256 + threadIdx.x;
    float4 v = ((const float4*)p)[i];
    half4v o = {(_Float16)__expf(v.x), (_Float16)__expf(v.y),
                (_Float16)__expf(v.z), (_Float16)__expf(v.w)};
    ((half4v*)E)[i] = o;
}

// ---------- E -> ET (f16 transpose) + F (fp8) + FT (fp8), 64x64 tiles ----------
__global__ __launch_bounds__(256) void k_trans16(const _Float16* __restrict__ E0in,
                                                 const _Float16* __restrict__ E1in,
                                                 _Float16* __restrict__ ET0,
                                                 _Float16* __restrict__ ET1,
                                                 unsigned int* __restrict__ F0,
                                                 unsigned int* __restrict__ F1,
                                                 unsigned int* __restrict__ FT0,
                                                 unsigned int* __restrict__ FT1) {
    int z = blockIdx.z;
    const _Float16* E = z ? E1in : E0in;
    _Float16* ET = z ? ET1 : ET0;
    unsigned int* F = z ? F1 : F0;
    unsigned int* FT = z ? FT1 : FT0;
    __shared__ _Float16 tile[64][72];
    int t = threadIdx.x;
    int r = t >> 2, c16 = (t & 3) * 16;
    int row = blockIdx.y * 64 + r;
    int col0 = blockIdx.x * 64 + c16;
    const _Float16* src = E + (size_t)row * HD + col0;
    half8v a = *(const half8v*)src;
    half8v b = *(const half8v*)(src + 8);
    uint4 fo;
    fo.x = pack4(a[0], a[1], a[2], a[3]);
    fo.y = pack4(a[4], a[5], a[6], a[7]);
    fo.z = pack4(b[0], b[1], b[2], b[3]);
    fo.w = pack4(b[4], b[5], b[6], b[7]);
    *(uint4*)(F + (size_t)row * (HD / 4) + (col0 >> 2)) = fo;
    *(half8v*)&tile[r][c16] = a;
    *(half8v*)&tile[r][c16 + 8] = b;
    __syncthreads();
    int j = r;  // output row within tile
    half8v oa, ob;
#pragma unroll
    for (int u = 0; u < 8; ++u) oa[u] = tile[c16 + u][j];
#pragma unroll
    for (int u = 0; u < 8; ++u) ob[u] = tile[c16 + 8 + u][j];
    size_t orow = (size_t)(blockIdx.x * 64 + j);
    _Float16* dst = ET + orow * HD + blockIdx.y * 64 + c16;
    *(half8v*)dst = oa;
    *(half8v*)(dst + 8) = ob;
    uint4 ft;
    ft.x = pack4(oa[0], oa[1], oa[2], oa[3]);
    ft.y = pack4(oa[4], oa[5], oa[6], oa[7]);
    ft.z = pack4(ob[0], ob[1], ob[2], ob[3]);
    ft.w = pack4(ob[4], ob[5], ob[6], ob[7]);
    *(uint4*)(FT + orow * (HD / 4) + ((blockIdx.y * 64 + c16) >> 2)) = ft;
}

// ---------- Sinkhorn phase: vout[row] = rcp( sum_j M[row][j] * vin[j] ) ----------
__global__ __launch_bounds__(256) void k_phase(const unsigned int* __restrict__ M0,
                                               const unsigned int* __restrict__ M1,
                                               const float* __restrict__ vin,
                                               float* __restrict__ vout, int first) {
    int b = blockIdx.x, t = threadIdx.x;
    int wave = t >> 6, lane = t & 63;
    int w = b * 4 + wave;  // 0..8191
    int m = w >> 12;
    int row = w & 4095;
    const unsigned int* r0 = (m ? M1 : M0) + (size_t)row * (HD / 4);
    const float* vm = vin + m * HD;
    float acc = 0.f;
#pragma unroll
    for (int c = 0; c < 4; ++c) {
        int j = c * 1024 + lane * 16;
        uint4 e = *(const uint4*)(r0 + (j >> 2));
        f32x2 a0 = __builtin_amdgcn_cvt_pk_f32_fp8((int)e.x, false);
        f32x2 a1 = __builtin_amdgcn_cvt_pk_f32_fp8((int)e.x, true);
        f32x2 a2 = __builtin_amdgcn_cvt_pk_f32_fp8((int)e.y, false);
        f32x2 a3 = __builtin_amdgcn_cvt_pk_f32_fp8((int)e.y, true);
        f32x2 a4 = __builtin_amdgcn_cvt_pk_f32_fp8((int)e.z, false);
        f32x2 a5 = __builtin_amdgcn_cvt_pk_f32_fp8((int)e.z, true);
        f32x2 a6 = __builtin_amdgcn_cvt_pk_f32_fp8((int)e.w, false);
        f32x2 a7 = __builtin_amdgcn_cvt_pk_f32_fp8((int)e.w, true);
        if (first) {
            acc += (a0.x + a0.y) + (a1.x + a1.y) + (a2.x + a2.y) + (a3.x + a3.y);
            acc += (a4.x + a4.y) + (a5.x + a5.y) + (a6.x + a6.y) + (a7.x + a7.y);
        } else {
            float4 s0 = *(const float4*)(vm + j);
            float4 s1 = *(const float4*)(vm + j + 4);
            float4 s2 = *(const float4*)(vm + j + 8);
            float4 s3 = *(const float4*)(vm + j + 12);
            acc += a0.x * s0.x + a0.y * s0.y + a1.x * s0.z + a1.y * s0.w;
            acc += a2.x * s1.x + a2.y * s1.y + a3.x * s1.z + a3.y * s1.w;
            acc += a4.x * s2.x + a4.y * s2.y + a5.x * s2.z + a5.y * s2.w;
            acc += a6.x * s3.x + a6.y * s3.y + a7.x * s3.z + a7.y * s3.w;
        }
    }
#pragma unroll
    for (int off = 32; off; off >>= 1) acc += __shfl_xor(acc, off, 64);
    if (lane == 0) vout[m * HD + row] = __builtin_amdgcn_rcpf(acc);
}

// ---------- GEMM C = A * B^T, 128x128 tile, BK=64, double-buffered LDS ----------
// global_load_lds staging with pre-swizzled source columns (rule 21): physical
// LDS slot s of row r holds logical k-slot s^(r&7); reads apply the same XOR.
__global__ __launch_bounds__(256) void k_gemm(const _Float16* __restrict__ A,
                                              const _Float16* __restrict__ B,
                                              float* __restrict__ Cp,
                                              int M, int N, int K, int kChunk) {
    __shared__ _Float16 As[2][128 * 64];  // 32 KB each pair-half
    __shared__ _Float16 Bs[2][128 * 64];
    int t = threadIdx.x;
    int w = t >> 6, lane = t & 63;
    int bn = blockIdx.x * 128, bm = blockIdx.y * 128;
    int k0beg = blockIdx.z * kChunk;
    int nt = kChunk >> 6;
    int rm = (w >> 1) * 64, wn = (w & 1) * 64;  // wave's 64x64 output quadrant
    int r16 = lane & 15, kq = lane >> 4;
    int h = r16 & 7;
    int srow = lane >> 3;
    int scol = ((lane & 7) ^ srow) * 8;  // pre-swizzled source column slot
    const _Float16* Abp = A + (size_t)(bm + w * 32 + srow) * K + scol;
    const _Float16* Bbp = B + (size_t)(bn + w * 32 + srow) * K + scol;
    f32x4 acc[4][4];
#pragma unroll
    for (int m2 = 0; m2 < 4; ++m2)
#pragma unroll
        for (int n2 = 0; n2 < 4; ++n2) acc[m2][n2] = (f32x4){0.f, 0.f, 0.f, 0.f};

    auto STAGE = [&](int d, int kk) {
        _Float16* AsW = &As[d][(w * 32) * 64];
        _Float16* BsW = &Bs[d][(w * 32) * 64];
#pragma unroll
        for (int i = 0; i < 4; ++i) {
            gload16(Abp + (size_t)(i * 8) * K + kk, AsW + i * 8 * 64);
            gload16(Bbp + (size_t)(i * 8) * K + kk, BsW + i * 8 * 64);
        }
    };

    STAGE(0, k0beg);
    for (int tt = 0; tt < nt; ++tt) {
        __syncthreads();  // tile tt staged (vmcnt drained); prev reads of other buf done
        if (tt + 1 < nt) STAGE((tt + 1) & 1, k0beg + (tt + 1) * 64);
        const _Float16* Ac = As[tt & 1];
        const _Float16* Bc = Bs[tt & 1];
#pragma unroll
        for (int s2 = 0; s2 < 2; ++s2) {
            half8v af[4], bf[4];
            int ls = (s2 * 4 + kq) ^ h;  // physical slot
#pragma unroll
            for (int m2 = 0; m2 < 4; ++m2)
                af[m2] = *(const half8v*)&Ac[(rm + m2 * 16 + r16) * 64 + ls * 8];
#pragma unroll
            for (int n2 = 0; n2 < 4; ++n2)
                bf[n2] = *(const half8v*)&Bc[(wn + n2 * 16 + r16) * 64 + ls * 8];
#pragma unroll
            for (int m2 = 0; m2 < 4; ++m2)
#pragma unroll
                for (int n2 = 0; n2 < 4; ++n2)
                    acc[m2][n2] = __builtin_amdgcn_mfma_f32_16x16x32_f16(af[m2], bf[n2],
                                                                         acc[m2][n2], 0, 0, 0);
        }
    }
    float* out = Cp + (size_t)blockIdx.z * M * N;
#pragma unroll
    for (int m2 = 0; m2 < 4; ++m2) {
#pragma unroll
        for (int n2 = 0; n2 < 4; ++n2) {
            int row0 = bm + rm + m2 * 16 + kq * 4;
            int col0 = bn + wn + n2 * 16 + r16;
#pragma unroll
            for (int rr = 0; rr < 4; ++rr)
                out[(size_t)(row0 + rr) * N + col0] = acc[m2][n2][rr];
        }
    }
}

// ---------- split-K reduce + fused Sinkhorn diagonal scales + relu + convert ----------
// mode 0: none; 1: v*=sc[col]; 2: v=relu(v*sc)*sc*4096; 3: v*=sc[col]/4096
__global__ __launch_bounds__(256) void k_reduce(const float* __restrict__ Cp, void* __restrict__ out,
                                                int MN, int KS, int mode,
                                                const float* __restrict__ sc, int of32) {
    size_t idx = ((size_t)blockIdx.x * 256 + threadIdx.x) * 8;
    if (idx >= (size_t)MN) return;
    float4 s0 = *(const float4*)(Cp + idx);
    float4 s1 = *(const float4*)(Cp + idx + 4);
    for (int z = 1; z < KS; ++z) {
        const float* p = Cp + (size_t)z * MN + idx;
        float4 v0 = *(const float4*)p;
        float4 v1 = *(const float4*)(p + 4);
        s0.x += v0.x; s0.y += v0.y; s0.z += v0.z; s0.w += v0.w;
        s1.x += v1.x; s1.y += v1.y; s1.z += v1.z; s1.w += v1.w;
    }
    if (mode) {
        int col = (int)(idx & (HD - 1));
        float4 a0 = *(const float4*)(sc + col);
        float4 a1 = *(const float4*)(sc + col + 4);
        if (mode == 1) {
            s0.x *= a0.x; s0.y *= a0.y; s0.z *= a0.z; s0.w *= a0.w;
            s1.x *= a1.x; s1.y *= a1.y; s1.z *= a1.z; s1.w *= a1.w;
        } else if (mode == 2) {
            s0.x = fmaxf(s0.x * a0.x, 0.f) * a0.x * 4096.f;
            s0.y = fmaxf(s0.y * a0.y, 0.f) * a0.y * 4096.f;
            s0.z = fmaxf(s0.z * a0.z, 0.f) * a0.z * 4096.f;
            s0.w = fmaxf(s0.w * a0.w, 0.f) * a0.w * 4096.f;
            s1.x = fmaxf(s1.x * a1.x, 0.f) * a1.x * 4096.f;
            s1.y = fmaxf(s1.y * a1.y, 0.f) * a1.y * 4096.f;
            s1.z = fmaxf(s1.z * a1.z, 0.f) * a1.z * 4096.f;
            s1.w = fmaxf(s1.w * a1.w, 0.f) * a1.w * 4096.f;
        } else {
            const float inv = 1.f / 4096.f;
            s0.x *= a0.x * inv; s0.y *= a0.y * inv; s0.z *= a0.z * inv; s0.w *= a0.w * inv;
            s1.x *= a1.x * inv; s1.y *= a1.y * inv; s1.z *= a1.z * inv; s1.w *= a1.w * inv;
        }
    }
    if (of32) {
        *(float4*)((float*)out + idx) = s0;
        *(float4*)((float*)out + idx + 4) = s1;
    } else {
        half8v o = {(_Float16)s0.x, (_Float16)s0.y, (_Float16)s0.z, (_Float16)s0.w,
                    (_Float16)s1.x, (_Float16)s1.y, (_Float16)s1.z, (_Float16)s1.w};
        *(half8v*)((_Float16*)out + idx) = o;
    }
}

extern "C" void kernel_launch(void* const* d_in, const int* in_sizes, int n_in,
                              void* d_out, int out_size, void* d_ws, size_t ws_size,
                              hipStream_t stream) {
    const float* x  = (const float*)d_in[0];
    const float* W1 = (const float*)d_in[1];
    const float* W2 = (const float*)d_in[3];
    const float* W3 = (const float*)d_in[5];
    const float* p0 = (const float*)d_in[7];
    const float* p1 = (const float*)d_in[8];

    char* ws = (char*)d_ws;
    size_t off = 0;
    auto alloc = [&](size_t bytes) -> void* {
        void* p = ws + off;
        off += (bytes + 255) & ~(size_t)255;
        return p;
    };
    _Float16* E0 = (_Float16*)alloc((size_t)HH * 2);
    _Float16* E1 = (_Float16*)alloc((size_t)HH * 2);
    _Float16* ET0 = (_Float16*)alloc((size_t)HH * 2);
    _Float16* ET1 = (_Float16*)alloc((size_t)HH * 2);
    unsigned int* F0 = (unsigned int*)alloc((size_t)HH);   // fp8; later aliased as Cp
    unsigned int* F1 = (unsigned int*)alloc((size_t)HH);
    unsigned int* FT0 = (unsigned int*)alloc((size_t)HH);  // fp8 T; later aliased as W2h
    unsigned int* FT1 = (unsigned int*)alloc((size_t)HH);
    _Float16* W1h = (_Float16*)alloc((size_t)4096 * 1024 * 2);
    _Float16* W3h = (_Float16*)alloc((size_t)1024 * 4096 * 2);
    _Float16* xh = (_Float16*)alloc(256 * 1024 * 2);
    _Float16* Aa = (_Float16*)alloc(256 * 4096 * 2);
    _Float16* Ab = (_Float16*)alloc(256 * 4096 * 2);
    float* invR = (float*)alloc(2 * 4096 * 4);
    float* invS = (float*)alloc(2 * 4096 * 4);
    float* Cp = (float*)F0;          // 33.5 MB (F0+F1), dead after sinkhorn
    _Float16* W2h = (_Float16*)FT0;  // 33.5 MB (FT0+FT1), dead after sinkhorn

    // precompute
    k_f32_to_f16<<<256, 256, 0, stream>>>(x, xh, 65536);
    k_f32_to_f16<<<4096, 256, 0, stream>>>(W1, W1h, 1048576);
    k_f32_to_f16<<<4096, 256, 0, stream>>>(W3, W3h, 1048576);
    k_exp<<<dim3(16384, 1, 2), 256, 0, stream>>>(p0, p1, E0, E1);
    k_trans16<<<dim3(64, 64, 2), 256, 0, stream>>>(E0, E1, ET0, ET1, F0, F1, FT0, FT1);

    // 20 Sinkhorn iterations
    for (int it = 0; it < 20; ++it) {
        k_phase<<<2048, 256, 0, stream>>>(F0, F1, invS, invR, it == 0);
        k_phase<<<2048, 256, 0, stream>>>(FT0, FT1, invR, invS, 0);
    }

    // W2 -> f16 into FT region (FT dead now)
    k_f32_to_f16<<<16384, 256, 0, stream>>>(W2, W2h, 4194304);

    // MLP chain; P = diag(r) E diag(s) fused into reduce epilogues
    k_gemm<<<dim3(32, 2, 8), 256, 0, stream>>>(xh, W1h, Cp, 256, 4096, 1024, 128);
    k_reduce<<<512, 256, 0, stream>>>(Cp, Aa, 1048576, 8, 1, invS, 0);
    k_gemm<<<dim3(32, 2, 8), 256, 0, stream>>>(Aa, E0, Cp, 256, 4096, 4096, 512);
    k_reduce<<<512, 256, 0, stream>>>(Cp, Ab, 1048576, 8, 2, invR, 0);
    k_gemm<<<dim3(32, 2, 8), 256, 0, stream>>>(Ab, ET0, Cp, 256, 4096, 4096, 512);
    k_reduce<<<512, 256, 0, stream>>>(Cp, Aa, 1048576, 8, 3, invS, 0);
    k_gemm<<<dim3(32, 2, 8), 256, 0, stream>>>(Aa, W2h, Cp, 256, 4096, 4096, 512);
    k_reduce<<<512, 256, 0, stream>>>(Cp, Ab, 1048576, 8, 1, invS + HD, 0);
    k_gemm<<<dim3(32, 2, 8), 256, 0, stream>>>(Ab, E1, Cp, 256, 4096, 4096, 512);
    k_reduce<<<512, 256, 0, stream>>>(Cp, Aa, 1048576, 8, 2, invR + HD, 0);
    k_gemm<<<dim3(32, 2, 8), 256, 0, stream>>>(Aa, ET1, Cp, 256, 4096, 4096, 512);
    k_reduce<<<512, 256, 0, stream>>>(Cp, Ab, 1048576, 8, 3, invS + HD, 0);
    k_gemm<<<dim3(8, 2, 32), 256, 0, stream>>>(Ab, W3h, Cp, 256, 1024, 4096, 128);
    k_reduce<<<128, 256, 0, stream>>>(Cp, d_out, 262144, 32, 0, nullptr, 1);

    (void)in_sizes; (void)n_in; (void)out_size; (void)ws_size;
}

// Round 5
// 872.717 us; speedup vs baseline: 1.0401x; 1.0244x over previous
//
#include <hip/hip_runtime.h>

typedef _Float16 half4v __attribute__((ext_vector_type(4)));
typedef _Float16 half8v __attribute__((ext_vector_type(8)));
typedef float f32x4 __attribute__((ext_vector_type(4)));
typedef float f32x2 __attribute__((ext_vector_type(2)));

#define HD 4096
#define HH (4096 * 4096)

__device__ __forceinline__ unsigned int pack4(float a, float b, float c, float d) {
    int w = 0;
    w = __builtin_amdgcn_cvt_pk_fp8_f32(a, b, w, false);
    w = __builtin_amdgcn_cvt_pk_fp8_f32(c, d, w, true);
    return (unsigned int)w;
}

__device__ __forceinline__ void gload16(const _Float16* g, _Float16* l) {
    __builtin_amdgcn_global_load_lds(
        (const __attribute__((address_space(1))) unsigned int*)g,
        (__attribute__((address_space(3))) unsigned int*)l, 16, 0, 0);
}

// ---------- f32 -> f16 (x only) ----------
__global__ __launch_bounds__(256) void k_f32_to_f16(const float* __restrict__ s,
                                                    _Float16* __restrict__ d, int n4) {
    int i = blockIdx.x * 256 + threadIdx.x;
    if (i >= n4) return;
    float4 v = ((const float4*)s)[i];
    half4v o = {(_Float16)v.x, (_Float16)v.y, (_Float16)v.z, (_Float16)v.w};
    ((half4v*)d)[i] = o;
}

// ---------- fused: p (f32) -> E (f16) + ET (f16 transpose) + F (fp8) + FT (fp8) ----------
// 64x64 tiles; F/FT derived from the same f16 values => exact transposes.
__global__ __launch_bounds__(256) void k_exptrans(const float* __restrict__ p0,
                                                  const float* __restrict__ p1,
                                                  _Float16* __restrict__ E0,
                                                  _Float16* __restrict__ E1,
                                                  _Float16* __restrict__ ET0,
                                                  _Float16* __restrict__ ET1,
                                                  unsigned int* __restrict__ F0,
                                                  unsigned int* __restrict__ F1,
                                                  unsigned int* __restrict__ FT0,
                                                  unsigned int* __restrict__ FT1) {
    int z = blockIdx.z;
    const float* p = z ? p1 : p0;
    _Float16* E = z ? E1 : E0;
    _Float16* ET = z ? ET1 : ET0;
    unsigned int* F = z ? F1 : F0;
    unsigned int* FT = z ? FT1 : FT0;
    __shared__ _Float16 tile[64][72];
    int t = threadIdx.x;
    int r = t >> 2, c16 = (t & 3) * 16;
    int row = blockIdx.y * 64 + r;
    int col0 = blockIdx.x * 64 + c16;
    const float* src = p + (size_t)row * HD + col0;
    float4 v0 = *(const float4*)(src);
    float4 v1 = *(const float4*)(src + 4);
    float4 v2 = *(const float4*)(src + 8);
    float4 v3 = *(const float4*)(src + 12);
    half8v a = {(_Float16)__expf(v0.x), (_Float16)__expf(v0.y),
                (_Float16)__expf(v0.z), (_Float16)__expf(v0.w),
                (_Float16)__expf(v1.x), (_Float16)__expf(v1.y),
                (_Float16)__expf(v1.z), (_Float16)__expf(v1.w)};
    half8v b = {(_Float16)__expf(v2.x), (_Float16)__expf(v2.y),
                (_Float16)__expf(v2.z), (_Float16)__expf(v2.w),
                (_Float16)__expf(v3.x), (_Float16)__expf(v3.y),
                (_Float16)__expf(v3.z), (_Float16)__expf(v3.w)};
    // E (row-major) write
    _Float16* ed = E + (size_t)row * HD + col0;
    *(half8v*)ed = a;
    *(half8v*)(ed + 8) = b;
    // F (fp8, row-major)
    uint4 fo;
    fo.x = pack4(a[0], a[1], a[2], a[3]);
    fo.y = pack4(a[4], a[5], a[6], a[7]);
    fo.z = pack4(b[0], b[1], b[2], b[3]);
    fo.w = pack4(b[4], b[5], b[6], b[7]);
    *(uint4*)(F + (size_t)row * (HD / 4) + (col0 >> 2)) = fo;
    // LDS transpose
    *(half8v*)&tile[r][c16] = a;
    *(half8v*)&tile[r][c16 + 8] = b;
    __syncthreads();
    int j = r;  // output row within tile
    half8v oa, ob;
#pragma unroll
    for (int u = 0; u < 8; ++u) oa[u] = tile[c16 + u][j];
#pragma unroll
    for (int u = 0; u < 8; ++u) ob[u] = tile[c16 + 8 + u][j];
    size_t orow = (size_t)(blockIdx.x * 64 + j);
    _Float16* dst = ET + orow * HD + blockIdx.y * 64 + c16;
    *(half8v*)dst = oa;
    *(half8v*)(dst + 8) = ob;
    uint4 ft;
    ft.x = pack4(oa[0], oa[1], oa[2], oa[3]);
    ft.y = pack4(oa[4], oa[5], oa[6], oa[7]);
    ft.z = pack4(ob[0], ob[1], ob[2], ob[3]);
    ft.w = pack4(ob[4], ob[5], ob[6], ob[7]);
    *(uint4*)(FT + orow * (HD / 4) + ((blockIdx.y * 64 + c16) >> 2)) = ft;
}

// ---------- Sinkhorn phase: vout[row] = rcp( sum_j M[row][j] * vin[j] ) ----------
__global__ __launch_bounds__(256) void k_phase(const unsigned int* __restrict__ M0,
                                               const unsigned int* __restrict__ M1,
                                               const float* __restrict__ vin,
                                               float* __restrict__ vout, int first) {
    int b = blockIdx.x, t = threadIdx.x;
    int wave = t >> 6, lane = t & 63;
    int w = b * 4 + wave;  // 0..8191
    int m = w >> 12;
    int row = w & 4095;
    const unsigned int* r0 = (m ? M1 : M0) + (size_t)row * (HD / 4);
    const float* vm = vin + m * HD;
    float acc = 0.f;
#pragma unroll
    for (int c = 0; c < 4; ++c) {
        int j = c * 1024 + lane * 16;
        uint4 e = *(const uint4*)(r0 + (j >> 2));
        f32x2 a0 = __builtin_amdgcn_cvt_pk_f32_fp8((int)e.x, false);
        f32x2 a1 = __builtin_amdgcn_cvt_pk_f32_fp8((int)e.x, true);
        f32x2 a2 = __builtin_amdgcn_cvt_pk_f32_fp8((int)e.y, false);
        f32x2 a3 = __builtin_amdgcn_cvt_pk_f32_fp8((int)e.y, true);
        f32x2 a4 = __builtin_amdgcn_cvt_pk_f32_fp8((int)e.z, false);
        f32x2 a5 = __builtin_amdgcn_cvt_pk_f32_fp8((int)e.z, true);
        f32x2 a6 = __builtin_amdgcn_cvt_pk_f32_fp8((int)e.w, false);
        f32x2 a7 = __builtin_amdgcn_cvt_pk_f32_fp8((int)e.w, true);
        if (first) {
            acc += (a0.x + a0.y) + (a1.x + a1.y) + (a2.x + a2.y) + (a3.x + a3.y);
            acc += (a4.x + a4.y) + (a5.x + a5.y) + (a6.x + a6.y) + (a7.x + a7.y);
        } else {
            float4 s0 = *(const float4*)(vm + j);
            float4 s1 = *(const float4*)(vm + j + 4);
            float4 s2 = *(const float4*)(vm + j + 8);
            float4 s3 = *(const float4*)(vm + j + 12);
            acc += a0.x * s0.x + a0.y * s0.y + a1.x * s0.z + a1.y * s0.w;
            acc += a2.x * s1.x + a2.y * s1.y + a3.x * s1.z + a3.y * s1.w;
            acc += a4.x * s2.x + a4.y * s2.y + a5.x * s2.z + a5.y * s2.w;
            acc += a6.x * s3.x + a6.y * s3.y + a7.x * s3.z + a7.y * s3.w;
        }
    }
#pragma unroll
    for (int off = 32; off; off >>= 1) acc += __shfl_xor(acc, off, 64);
    if (lane == 0) vout[m * HD + row] = __builtin_amdgcn_rcpf(acc);
}

// ---------- GEMM C = A * B^T, 128x128 tile, BK=64, double-buffered ----------
// BF32=0: B f16, global_load_lds staging, XOR-swizzled (rule 21).
// BF32=1: B f32, reg-staged + in-flight f16 convert, +8-padded LDS (conflict-free reads);
//         prefetch issued before MFMA so global latency hides under compute.
template <int BF32>
__global__ __launch_bounds__(256) void k_gemm(const _Float16* __restrict__ A,
                                              const void* __restrict__ Bv,
                                              float* __restrict__ Cp,
                                              int M, int N, int K, int kChunk) {
    constexpr int BROW = BF32 ? 72 : 64;
    __shared__ _Float16 As[2][128 * 64];
    __shared__ _Float16 Bs[2][128 * BROW];
    int t = threadIdx.x;
    int w = t >> 6, lane = t & 63;
    int bn = blockIdx.x * 128, bm = blockIdx.y * 128;
    int k0beg = blockIdx.z * kChunk;
    int nt = kChunk >> 6;
    int rm = (w >> 1) * 64, wn = (w & 1) * 64;  // wave's 64x64 quadrant
    int r16 = lane & 15, kq = lane >> 4;
    int h = r16 & 7;
    int srow = lane >> 3;
    int scol = ((lane & 7) ^ srow) * 8;  // pre-swizzled source k-slot
    const _Float16* Abp = A + (size_t)(bm + w * 32 + srow) * K + scol;
    const _Float16* Bhp = (const _Float16*)Bv + (size_t)(bn + w * 32 + srow) * K + scol;
    int br = t >> 1, bk = (t & 1) * 32;  // mode-1 B mapping
    const float* Bfp = (const float*)Bv + (size_t)(bn + br) * K + bk;
    float4 breg[8];
    f32x4 acc[4][4] = {};

    auto STAGEA = [&](int d, int kk) {
        _Float16* AsW = &As[d][(w * 32) * 64];
#pragma unroll
        for (int i = 0; i < 4; ++i)
            gload16(Abp + (size_t)(i * 8) * K + kk, AsW + i * 8 * 64);
    };
    auto STAGEB16 = [&](int d, int kk) {
        _Float16* BsW = &Bs[d][(w * 32) * 64];
#pragma unroll
        for (int i = 0; i < 4; ++i)
            gload16(Bhp + (size_t)(i * 8) * K + kk, BsW + i * 8 * 64);
    };
    auto LOADBF = [&](int kk) {
#pragma unroll
        for (int u = 0; u < 8; ++u) breg[u] = *(const float4*)(Bfp + kk + u * 4);
    };
    auto WRITEBF = [&](int d) {
        _Float16* bp = &Bs[d][br * 72 + bk];
#pragma unroll
        for (int u = 0; u < 4; ++u) {
            float4 f0 = breg[2 * u], f1 = breg[2 * u + 1];
            half8v hv = {(_Float16)f0.x, (_Float16)f0.y, (_Float16)f0.z, (_Float16)f0.w,
                         (_Float16)f1.x, (_Float16)f1.y, (_Float16)f1.z, (_Float16)f1.w};
            *(half8v*)(bp + u * 8) = hv;
        }
    };
    auto MFMAS = [&](int d) {
#pragma unroll
        for (int s2 = 0; s2 < 2; ++s2) {
            half8v af[4], bf[4];
            int ls = (s2 * 4 + kq) ^ h;
#pragma unroll
            for (int m2 = 0; m2 < 4; ++m2)
                af[m2] = *(const half8v*)&As[d][(rm + m2 * 16 + r16) * 64 + ls * 8];
            if constexpr (BF32) {
#pragma unroll
                for (int n2 = 0; n2 < 4; ++n2)
                    bf[n2] = *(const half8v*)&Bs[d][(wn + n2 * 16 + r16) * 72 + s2 * 32 + kq * 8];
            } else {
#pragma unroll
                for (int n2 = 0; n2 < 4; ++n2)
                    bf[n2] = *(const half8v*)&Bs[d][(wn + n2 * 16 + r16) * 64 + ls * 8];
            }
#pragma unroll
            for (int m2 = 0; m2 < 4; ++m2)
#pragma unroll
                for (int n2 = 0; n2 < 4; ++n2)
                    acc[m2][n2] = __builtin_amdgcn_mfma_f32_16x16x32_f16(af[m2], bf[n2],
                                                                         acc[m2][n2], 0, 0, 0);
        }
    };

    if constexpr (!BF32) {
        STAGEA(0, k0beg);
        STAGEB16(0, k0beg);
        for (int tt = 0; tt < nt; ++tt) {
            __syncthreads();  // tile tt staged (vmcnt drained); prior readers done
            if (tt + 1 < nt) {
                STAGEA((tt + 1) & 1, k0beg + (tt + 1) * 64);
                STAGEB16((tt + 1) & 1, k0beg + (tt + 1) * 64);
            }
            MFMAS(tt & 1);  // overlaps in-flight next-tile loads
        }
    } else {
        LOADBF(k0beg);
        STAGEA(0, k0beg);
        __syncthreads();  // A0 in LDS; breg0 loaded
        WRITEBF(0);
        __syncthreads();  // B0 visible
        for (int tt = 0; tt < nt; ++tt) {
            int cur = tt & 1, nxt = cur ^ 1;
            if (tt + 1 < nt) {
                STAGEA(nxt, k0beg + (tt + 1) * 64);
                LOADBF(k0beg + (tt + 1) * 64);
            }
            MFMAS(cur);       // prefetch latency hides here
            __syncthreads();  // readers done; prefetch drained
            if (tt + 1 < nt) WRITEBF(nxt);
            __syncthreads();  // Bs[nxt] visible
        }
    }

    float* out = Cp + (size_t)blockIdx.z * M * N;
#pragma unroll
    for (int m2 = 0; m2 < 4; ++m2) {
#pragma unroll
        for (int n2 = 0; n2 < 4; ++n2) {
            int row0 = bm + rm + m2 * 16 + kq * 4;
            int col0 = bn + wn + n2 * 16 + r16;
#pragma unroll
            for (int rr = 0; rr < 4; ++rr)
                out[(size_t)(row0 + rr) * N + col0] = acc[m2][n2][rr];
        }
    }
}

// ---------- split-K reduce + fused Sinkhorn diagonal scales + relu + convert ----------
// mode 0: none; 1: v*=sc[col]; 2: v=relu(v*sc)*sc*4096; 3: v*=sc[col]/4096
__global__ __launch_bounds__(256) void k_reduce(const float* __restrict__ Cp, void* __restrict__ out,
                                                int MN, int KS, int mode,
                                                const float* __restrict__ sc, int of32) {
    size_t idx = ((size_t)blockIdx.x * 256 + threadIdx.x) * 8;
    if (idx >= (size_t)MN) return;
    float4 s0 = *(const float4*)(Cp + idx);
    float4 s1 = *(const float4*)(Cp + idx + 4);
    for (int z = 1; z < KS; ++z) {
        const float* p = Cp + (size_t)z * MN + idx;
        float4 v0 = *(const float4*)p;
        float4 v1 = *(const float4*)(p + 4);
        s0.x += v0.x; s0.y += v0.y; s0.z += v0.z; s0.w += v0.w;
        s1.x += v1.x; s1.y += v1.y; s1.z += v1.z; s1.w += v1.w;
    }
    if (mode) {
        int col = (int)(idx & (HD - 1));
        float4 a0 = *(const float4*)(sc + col);
        float4 a1 = *(const float4*)(sc + col + 4);
        if (mode == 1) {
            s0.x *= a0.x; s0.y *= a0.y; s0.z *= a0.z; s0.w *= a0.w;
            s1.x *= a1.x; s1.y *= a1.y; s1.z *= a1.z; s1.w *= a1.w;
        } else if (mode == 2) {
            s0.x = fmaxf(s0.x * a0.x, 0.f) * a0.x * 4096.f;
            s0.y = fmaxf(s0.y * a0.y, 0.f) * a0.y * 4096.f;
            s0.z = fmaxf(s0.z * a0.z, 0.f) * a0.z * 4096.f;
            s0.w = fmaxf(s0.w * a0.w, 0.f) * a0.w * 4096.f;
            s1.x = fmaxf(s1.x * a1.x, 0.f) * a1.x * 4096.f;
            s1.y = fmaxf(s1.y * a1.y, 0.f) * a1.y * 4096.f;
            s1.z = fmaxf(s1.z * a1.z, 0.f) * a1.z * 4096.f;
            s1.w = fmaxf(s1.w * a1.w, 0.f) * a1.w * 4096.f;
        } else {
            const float inv = 1.f / 4096.f;
            s0.x *= a0.x * inv; s0.y *= a0.y * inv; s0.z *= a0.z * inv; s0.w *= a0.w * inv;
            s1.x *= a1.x * inv; s1.y *= a1.y * inv; s1.z *= a1.z * inv; s1.w *= a1.w * inv;
        }
    }
    if (of32) {
        *(float4*)((float*)out + idx) = s0;
        *(float4*)((float*)out + idx + 4) = s1;
    } else {
        half8v o = {(_Float16)s0.x, (_Float16)s0.y, (_Float16)s0.z, (_Float16)s0.w,
                    (_Float16)s1.x, (_Float16)s1.y, (_Float16)s1.z, (_Float16)s1.w};
        *(half8v*)((_Float16*)out + idx) = o;
    }
}

extern "C" void kernel_launch(void* const* d_in, const int* in_sizes, int n_in,
                              void* d_out, int out_size, void* d_ws, size_t ws_size,
                              hipStream_t stream) {
    const float* x  = (const float*)d_in[0];
    const float* W1 = (const float*)d_in[1];
    const float* W2 = (const float*)d_in[3];
    const float* W3 = (const float*)d_in[5];
    const float* p0 = (const float*)d_in[7];
    const float* p1 = (const float*)d_in[8];

    char* ws = (char*)d_ws;
    size_t off = 0;
    auto alloc = [&](size_t bytes) -> void* {
        void* p = ws + off;
        off += (bytes + 255) & ~(size_t)255;
        return p;
    };
    _Float16* E0 = (_Float16*)alloc((size_t)HH * 2);
    _Float16* E1 = (_Float16*)alloc((size_t)HH * 2);
    _Float16* ET0 = (_Float16*)alloc((size_t)HH * 2);
    _Float16* ET1 = (_Float16*)alloc((size_t)HH * 2);
    unsigned int* F0 = (unsigned int*)alloc((size_t)HH);   // fp8; aliased as Cp later
    unsigned int* F1 = (unsigned int*)alloc((size_t)HH);
    unsigned int* FT0 = (unsigned int*)alloc((size_t)HH);
    unsigned int* FT1 = (unsigned int*)alloc((size_t)HH);
    _Float16* xh = (_Float16*)alloc(256 * 1024 * 2);
    _Float16* Aa = (_Float16*)alloc(256 * 4096 * 2);
    _Float16* Ab = (_Float16*)alloc(256 * 4096 * 2);
    float* invR = (float*)alloc(2 * 4096 * 4);
    float* invS = (float*)alloc(2 * 4096 * 4);
    float* Cp = (float*)F0;  // 32 MB (F0+F1), dead after sinkhorn

    // precompute: x convert + fused exp/transpose/quantize
    k_f32_to_f16<<<256, 256, 0, stream>>>(x, xh, 65536);
    k_exptrans<<<dim3(64, 64, 2), 256, 0, stream>>>(p0, p1, E0, E1, ET0, ET1, F0, F1, FT0, FT1);

    // 20 Sinkhorn iterations
    for (int it = 0; it < 20; ++it) {
        k_phase<<<2048, 256, 0, stream>>>(F0, F1, invS, invR, it == 0);
        k_phase<<<2048, 256, 0, stream>>>(FT0, FT1, invR, invS, 0);
    }

    // MLP chain; P = diag(r) E diag(s) fused into reduce epilogues; W* read as f32 in GEMM
    k_gemm<1><<<dim3(32, 2, 8), 256, 0, stream>>>(xh, W1, Cp, 256, 4096, 1024, 128);
    k_reduce<<<512, 256, 0, stream>>>(Cp, Aa, 1048576, 8, 1, invS, 0);
    k_gemm<0><<<dim3(32, 2, 8), 256, 0, stream>>>(Aa, E0, Cp, 256, 4096, 4096, 512);
    k_reduce<<<512, 256, 0, stream>>>(Cp, Ab, 1048576, 8, 2, invR, 0);
    k_gemm<0><<<dim3(32, 2, 8), 256, 0, stream>>>(Ab, ET0, Cp, 256, 4096, 4096, 512);
    k_reduce<<<512, 256, 0, stream>>>(Cp, Aa, 1048576, 8, 3, invS, 0);
    k_gemm<1><<<dim3(32, 2, 8), 256, 0, stream>>>(Aa, W2, Cp, 256, 4096, 4096, 512);
    k_reduce<<<512, 256, 0, stream>>>(Cp, Ab, 1048576, 8, 1, invS + HD, 0);
    k_gemm<0><<<dim3(32, 2, 8), 256, 0, stream>>>(Ab, E1, Cp, 256, 4096, 4096, 512);
    k_reduce<<<512, 256, 0, stream>>>(Cp, Aa, 1048576, 8, 2, invR + HD, 0);
    k_gemm<0><<<dim3(32, 2, 8), 256, 0, stream>>>(Aa, ET1, Cp, 256, 4096, 4096, 512);
    k_reduce<<<512, 256, 0, stream>>>(Cp, Ab, 1048576, 8, 3, invS + HD, 0);
    k_gemm<1><<<dim3(8, 2, 32), 256, 0, stream>>>(Ab, W3, Cp, 256, 1024, 4096, 128);
    k_reduce<<<128, 256, 0, stream>>>(Cp, d_out, 262144, 32, 0, nullptr, 1);

    (void)in_sizes; (void)n_in; (void)out_size; (void)ws_size;
}